// Round 3
// baseline (148.318 us; speedup 1.0000x reference)
//
#include <hip/hip_runtime.h>
#include <cstdint>
#include <cstddef>

#define N_PTS 4096
#define KDIM  512
#define NFEAT 5

typedef __attribute__((ext_vector_type(8))) short bf16x8;   // 8 bf16 = 4 VGPRs
typedef __attribute__((ext_vector_type(4))) float f32x4;
typedef uint32_t u32;

// round-to-nearest-even fp32 -> bf16 (inputs finite)
__device__ inline unsigned short f2bf(float f) {
  union { float f; u32 u; } v; v.f = f;
  u32 r = (v.u + 0x7fffu + ((v.u >> 16) & 1u)) >> 16;
  return (unsigned short)r;
}

__device__ inline void bf2f2(u32 u, float& a, float& b) {
  union { u32 u; float f; } x, y;
  x.u = u << 16; y.u = u & 0xffff0000u;
  a = x.f; b = y.f;
}

// async global->LDS, 16B per lane (dest must be wave-uniform base + lane*16)
__device__ inline void load_lds16(const void* g, void* l) {
  __builtin_amdgcn_global_load_lds(
      (const __attribute__((address_space(1))) void*)g,
      (__attribute__((address_space(3))) void*)l, 16, 0, 0);
}

// ---------------------------------------------------------------------------
// Kernel 1: X (fp32) -> bf16 + per-row squared norms
// ---------------------------------------------------------------------------
__global__ __launch_bounds__(256) void prep_kernel(const float* __restrict__ X,
                                                   short* __restrict__ Xb,
                                                   float* __restrict__ sq) {
  const int row = blockIdx.x;
  const int t = threadIdx.x;
  const float2 v = ((const float2*)(X + (size_t)row * KDIM))[t];
  short2 b;
  b.x = (short)f2bf(v.x);
  b.y = (short)f2bf(v.y);
  ((short2*)(Xb + (size_t)row * KDIM))[t] = b;
  float s = v.x * v.x + v.y * v.y;
#pragma unroll
  for (int off = 32; off; off >>= 1) s += __shfl_down(s, off);
  __shared__ float ws[4];
  if ((t & 63) == 0) ws[t >> 6] = s;
  __syncthreads();
  if (t == 0) sq[row] = ws[0] + ws[1] + ws[2] + ws[3];
}

// ---------------------------------------------------------------------------
// Kernel 2 (symmetric): upper-triangular 128x128 tiles (bm <= bn), BK=64.
// Epilogue: swizzled 32KB LDS tile (bf16) -> canonical row-major coalesced
// stores of BOTH the direct tile and (for bm<bn) the mirrored tile.
// LDS swizzle: 16B granule g at row r stored at g ^ ((r>>3)&15); makes
// row-major b128 reads AND 8-row column-granule u16 reads conflict-light.
// ---------------------------------------------------------------------------
__global__ __launch_bounds__(256, 2) void dist_kernel(
    const short* __restrict__ Xb, const float* __restrict__ sq,
    unsigned short* __restrict__ Dw, float* __restrict__ gsum) {
  const int bm = blockIdx.y, bn = blockIdx.x;
  if (bm > bn) return;

  __shared__ uint4 smem4[2048];           // 32 KB, aliased: staging | transpose tile
  short* As = (short*)smem4;              // 128x64 bf16 (16 KB)
  short* Bs = (short*)smem4 + 128 * 64;   // 128x64 bf16 (16 KB)
  char* T = (char*)smem4;                 // 128 rows x 256 B swizzled bf16 tile

  const int tid = threadIdx.x;
  const int lane = tid & 63;
  const int wid = tid >> 6;
  const int wave_m = wid >> 1, wave_n = wid & 1;
  const int lhi = lane >> 4, llo = lane & 15;

  f32x4 acc[4][4];
#pragma unroll
  for (int i = 0; i < 4; ++i)
#pragma unroll
    for (int j = 0; j < 4; ++j) acc[i][j] = (f32x4){0.f, 0.f, 0.f, 0.f};

  // staging: thread t loads row (g*32 + t>>3), k-chunk (t&7)*8
  const int srow = tid >> 3;
  const int scol = (tid & 7) * 8;
  const size_t ga0 = (size_t)(bm * 128 + srow) * KDIM + scol;
  const size_t gb0 = (size_t)(bn * 128 + srow) * KDIM + scol;

  for (int kt = 0; kt < KDIM / 64; ++kt) {
    const int koff = kt * 64;
#pragma unroll
    for (int g = 0; g < 4; ++g) {
      load_lds16(Xb + ga0 + (size_t)g * 32 * KDIM + koff, (char*)As + g * 4096 + tid * 16);
      load_lds16(Xb + gb0 + (size_t)g * 32 * KDIM + koff, (char*)Bs + g * 4096 + tid * 16);
    }
    __syncthreads();

    bf16x8 a[2][4], b[2][4];
#pragma unroll
    for (int h = 0; h < 2; ++h)
#pragma unroll
      for (int i = 0; i < 4; ++i) {
        a[h][i] = *(const bf16x8*)&As[(wave_m * 64 + i * 16 + llo) * 64 + h * 32 + lhi * 8];
        b[h][i] = *(const bf16x8*)&Bs[(wave_n * 64 + i * 16 + llo) * 64 + h * 32 + lhi * 8];
      }
#pragma unroll
    for (int h = 0; h < 2; ++h)
#pragma unroll
      for (int i = 0; i < 4; ++i)
#pragma unroll
        for (int j = 0; j < 4; ++j)
          acc[i][j] =
              __builtin_amdgcn_mfma_f32_16x16x32_bf16(a[h][i], b[h][j], acc[i][j], 0, 0, 0);
    __syncthreads();
  }

  // ---- Epilogue phase 1: d = sqrt(max(.,0)), scatter bf16 into swizzled T ----
  // C/D layout: col=lane&15, row=(lane>>4)*4+reg
  float lsum = 0.f;
  const int gi0 = bm * 128, gj0 = bn * 128;
  const int r_base = wave_m * 64 + lhi * 4;
  const int c_base = wave_n * 64 + llo;
  float sqj[4];
#pragma unroll
  for (int j = 0; j < 4; ++j) sqj[j] = sq[gj0 + c_base + j * 16];

#pragma unroll
  for (int i = 0; i < 4; ++i) {
#pragma unroll
    for (int rr = 0; rr < 4; ++rr) {
      const int r = r_base + i * 16 + rr;
      const float sqi = sq[gi0 + r];
      const int swz = (r >> 3) & 15;
      const int rbyte = r * 256;
#pragma unroll
      for (int j = 0; j < 4; ++j) {
        const int c = c_base + j * 16;
        float d2 = sqi + sqj[j] - 2.f * acc[i][j][rr];
        float dd = sqrtf(fmaxf(d2, 0.f));
        if (gi0 + r == gj0 + c) dd = 0.f;  // exact-zero diagonal
        lsum += dd;
        *(unsigned short*)(T + rbyte + (((c >> 3) ^ swz) << 4) + ((c & 7) << 1)) = f2bf(dd);
      }
    }
  }
#pragma unroll
  for (int off = 32; off; off >>= 1) lsum += __shfl_down(lsum, off);
  if (lane == 0) {
    const float scale = (bm == bn) ? 1.f : 2.f;  // mirror counted once
    atomicAdd(gsum, scale * lsum);
  }
  __syncthreads();

  // ---- Phase 2: direct tile, row-major b128 reads + coalesced 16B stores ----
  const int tA = tid & 15, tB = tid >> 4;
#pragma unroll
  for (int s = 0; s < 8; ++s) {
    const int r = s * 16 + tB;
    const int g = tA ^ ((r >> 3) & 15);
    const uint4 v = *(const uint4*)(T + r * 256 + g * 16);
    *(uint4*)&Dw[(size_t)(gi0 + r) * N_PTS + gj0 + tA * 8] = v;
  }

  // ---- Phase 3: mirrored tile via column-granule reads (bm < bn only) ----
  if (bm != bn) {
#pragma unroll
    for (int s = 0; s < 8; ++s) {
      const int mr = s * 16 + tB;              // mirror row = T column
      const int base = (((mr >> 3) ^ tA) << 4) + ((mr & 7) << 1);
      u32 p[4];
#pragma unroll
      for (int k = 0; k < 4; ++k) {
        const u32 lo = *(const unsigned short*)(T + (tA * 8 + 2 * k) * 256 + base);
        const u32 hi = *(const unsigned short*)(T + (tA * 8 + 2 * k + 1) * 256 + base);
        p[k] = lo | (hi << 16);
      }
      *(uint4*)&Dw[(size_t)(gj0 + mr) * N_PTS + gi0 + tA * 8] =
          (uint4){p[0], p[1], p[2], p[3]};
    }
  }
}

// ---------------------------------------------------------------------------
// Kernel 3: pure elementwise streaming: out = sum_f exp(-d/(bw*mult_f))
// ---------------------------------------------------------------------------
__global__ __launch_bounds__(256) void rbf_kernel(
    const unsigned short* __restrict__ Dw, const float* __restrict__ gsum,
    const float* __restrict__ mult, float* __restrict__ out) {
  const float bw = *gsum * (1.0f / ((float)N_PTS * (float)(N_PTS - 1)));
  float c[NFEAT];
#pragma unroll
  for (int f = 0; f < NFEAT; ++f) c[f] = -1.0f / (bw * mult[f]);

  const size_t total = (size_t)N_PTS * N_PTS / 8;  // uint4 chunks of 8 bf16
  const size_t stride = (size_t)gridDim.x * blockDim.x;
  const uint4* D8 = (const uint4*)Dw;
  for (size_t idx = (size_t)blockIdx.x * blockDim.x + threadIdx.x; idx < total;
       idx += stride) {
    const uint4 pck = D8[idx];
    float v[8];
    bf2f2(pck.x, v[0], v[1]);
    bf2f2(pck.y, v[2], v[3]);
    bf2f2(pck.z, v[4], v[5]);
    bf2f2(pck.w, v[6], v[7]);
    float o[8];
#pragma unroll
    for (int e = 0; e < 8; ++e) {
      float a = 0.f;
#pragma unroll
      for (int f = 0; f < NFEAT; ++f) a += __expf(v[e] * c[f]);
      o[e] = a;
    }
    float4* dst = (float4*)(out + idx * 8);
    dst[0] = (float4){o[0], o[1], o[2], o[3]};
    dst[1] = (float4){o[4], o[5], o[6], o[7]};
  }
}

extern "C" void kernel_launch(void* const* d_in, const int* in_sizes, int n_in,
                              void* d_out, int out_size, void* d_ws, size_t ws_size,
                              hipStream_t stream) {
  const float* X = (const float*)d_in[0];
  const float* mult = (const float*)d_in[1];
  float* out = (float*)d_out;

  // ws: gsum@0 | sq@1024 (16KB) | Xb@17408 (4MB) | Dw bf16 full @ +4MB (32MB)
  char* ws = (char*)d_ws;
  float* gsum = (float*)ws;
  float* sq = (float*)(ws + 1024);
  short* Xb = (short*)(ws + 1024 + N_PTS * sizeof(float));
  unsigned short* Dw = (unsigned short*)(ws + 1024 + N_PTS * sizeof(float) +
                                         (size_t)N_PTS * KDIM * sizeof(short));

  hipMemsetAsync(gsum, 0, 256, stream);
  prep_kernel<<<N_PTS, 256, 0, stream>>>(X, Xb, sq);
  dist_kernel<<<dim3(32, 32), 256, 0, stream>>>(Xb, sq, Dw, gsum);
  rbf_kernel<<<2048, 256, 0, stream>>>(Dw, gsum, mult, out);
}

// Round 4
// 126.791 us; speedup vs baseline: 1.1698x; 1.1698x over previous
//
#include <hip/hip_runtime.h>
#include <cstdint>
#include <cstddef>

#define N_PTS 4096
#define KDIM  512
#define NFEAT 5

typedef __attribute__((ext_vector_type(8))) short bf16x8;   // 8 bf16 = 4 VGPRs
typedef __attribute__((ext_vector_type(4))) float f32x4;
typedef uint32_t u32;

// round-to-nearest-even fp32 -> bf16 (inputs finite)
__device__ inline unsigned short f2bf(float f) {
  union { float f; u32 u; } v; v.f = f;
  u32 r = (v.u + 0x7fffu + ((v.u >> 16) & 1u)) >> 16;
  return (unsigned short)r;
}

__device__ inline void bf2f2(u32 u, float& a, float& b) {
  union { u32 u; float f; } x, y;
  x.u = u << 16; y.u = u & 0xffff0000u;
  a = x.f; b = y.f;
}

// async global->LDS, 16B per lane (dest is wave-uniform base + lane*16)
__device__ inline void load_lds16(const void* g, void* l) {
  __builtin_amdgcn_global_load_lds(
      (const __attribute__((address_space(1))) void*)g,
      (__attribute__((address_space(3))) void*)l, 16, 0, 0);
}

// ---------------------------------------------------------------------------
// Kernel 1: X (fp32) -> bf16 + per-row squared norms; also zeroes gsum
// ---------------------------------------------------------------------------
__global__ __launch_bounds__(256) void prep_kernel(const float* __restrict__ X,
                                                   short* __restrict__ Xb,
                                                   float* __restrict__ sq,
                                                   float* __restrict__ gsum) {
  if (blockIdx.x == 0 && threadIdx.x == 0) *gsum = 0.f;
  const int row = blockIdx.x;
  const int t = threadIdx.x;
  const float2 v = ((const float2*)(X + (size_t)row * KDIM))[t];
  short2 b;
  b.x = (short)f2bf(v.x);
  b.y = (short)f2bf(v.y);
  ((short2*)(Xb + (size_t)row * KDIM))[t] = b;
  float s = v.x * v.x + v.y * v.y;
#pragma unroll
  for (int off = 32; off; off >>= 1) s += __shfl_down(s, off);
  __shared__ float ws[4];
  if ((t & 63) == 0) ws[t >> 6] = s;
  __syncthreads();
  if (t == 0) sq[row] = ws[0] + ws[1] + ws[2] + ws[3];
}

// ---------------------------------------------------------------------------
// Kernel 2: full grid of 128x128 tiles, BK=64, mfma_f32_16x16x32_bf16.
// LDS XOR swizzle: slot (t&7) of row (t>>3) holds global k-granule
// (t&7)^(row&7), so fragment ds_read_b128 spreads over all 8 bank groups
// (2-way max = free). Epilogue stores bf16 distances FRAGMENT-ORDERED
// (two dense 16B stores per lane per i) — no transpose anywhere.
// Dw tile layout: [tile=bm*32+bn][wave][i][half][lane][8 bf16].
// ---------------------------------------------------------------------------
__global__ __launch_bounds__(256, 3) void dist_kernel(
    const short* __restrict__ Xb, const float* __restrict__ sq,
    unsigned short* __restrict__ Dw, float* __restrict__ gsum) {
  __shared__ short As[128 * 64];   // 16 KB
  __shared__ short Bs[128 * 64];   // 16 KB
  __shared__ float red[4];

  const int tid = threadIdx.x;
  const int lane = tid & 63;
  const int wid = tid >> 6;
  const int wave_m = wid >> 1, wave_n = wid & 1;
  const int lhi = lane >> 4, llo = lane & 15;
  const int bm = blockIdx.y, bn = blockIdx.x;

  f32x4 acc[4][4];
#pragma unroll
  for (int i = 0; i < 4; ++i)
#pragma unroll
    for (int j = 0; j < 4; ++j) acc[i][j] = (f32x4){0.f, 0.f, 0.f, 0.f};

  // staging: lane t fetches row (t>>3), k-granule (t&7)^(row&7) -> LDS slot t
  const int srow = tid >> 3;                 // 0..31
  const int sgran = (tid & 7) ^ (srow & 7);  // XOR-swizzled granule
  const size_t ga0 = (size_t)(bm * 128 + srow) * KDIM + sgran * 8;
  const size_t gb0 = (size_t)(bn * 128 + srow) * KDIM + sgran * 8;

  for (int kt = 0; kt < KDIM / 64; ++kt) {
    const int koff = kt * 64;
#pragma unroll
    for (int g = 0; g < 4; ++g) {
      load_lds16(Xb + ga0 + (size_t)g * 32 * KDIM + koff, (char*)As + g * 4096 + tid * 16);
      load_lds16(Xb + gb0 + (size_t)g * 32 * KDIM + koff, (char*)Bs + g * 4096 + tid * 16);
    }
    __syncthreads();

#pragma unroll
    for (int h = 0; h < 2; ++h) {
      bf16x8 a[4], b[4];
#pragma unroll
      for (int i = 0; i < 4; ++i) {
        const int ra = wave_m * 64 + i * 16 + llo;
        const int rb = wave_n * 64 + i * 16 + llo;
        const int c = h * 4 + lhi;
        a[i] = *(const bf16x8*)&As[ra * 64 + ((c ^ (ra & 7)) << 3)];
        b[i] = *(const bf16x8*)&Bs[rb * 64 + ((c ^ (rb & 7)) << 3)];
      }
#pragma unroll
      for (int i = 0; i < 4; ++i)
#pragma unroll
        for (int j = 0; j < 4; ++j)
          acc[i][j] =
              __builtin_amdgcn_mfma_f32_16x16x32_bf16(a[i], b[j], acc[i][j], 0, 0, 0);
    }
    __syncthreads();
  }

  // epilogue: C/D layout col=lane&15, row=(lane>>4)*4+reg
  float lsum = 0.f;
  const int gi0 = bm * 128, gj0 = bn * 128;
  const int r_base = wave_m * 64 + lhi * 4;
  const int c_base = wave_n * 64 + llo;
  float sqj[4];
#pragma unroll
  for (int j = 0; j < 4; ++j) sqj[j] = sq[gj0 + c_base + j * 16];

  const size_t tile_base =
      ((size_t)(bm * 32 + bn)) * 16384 + (size_t)wid * 4096;

#pragma unroll
  for (int i = 0; i < 4; ++i) {
    union { unsigned short s[16]; uint4 q[2]; } pk;
#pragma unroll
    for (int rr = 0; rr < 4; ++rr) {
      const int r = r_base + i * 16 + rr;
      const float sqi = sq[gi0 + r];
#pragma unroll
      for (int j = 0; j < 4; ++j) {
        const int c = c_base + j * 16;
        float d2 = sqi + sqj[j] - 2.f * acc[i][j][rr];
        float dd = sqrtf(fmaxf(d2, 0.f));
        if (gi0 + r == gj0 + c) dd = 0.f;  // exact-zero diagonal
        lsum += dd;
        pk.s[rr * 4 + j] = f2bf(dd);
      }
    }
    unsigned short* dst = Dw + tile_base + (size_t)i * 1024;
    *(uint4*)(dst + lane * 8) = pk.q[0];
    *(uint4*)(dst + 512 + lane * 8) = pk.q[1];
  }

#pragma unroll
  for (int off = 32; off; off >>= 1) lsum += __shfl_down(lsum, off);
  if (lane == 0) red[wid] = lsum;
  __syncthreads();
  if (tid == 0) atomicAdd(gsum, red[0] + red[1] + red[2] + red[3]);
}

// ---------------------------------------------------------------------------
// Kernel 3: read fragment-ordered bf16 Dw (dense uint4), 5-way exp,
// write canonical fp32 out (64B-segment dword stores per 16-lane group).
// ---------------------------------------------------------------------------
__global__ __launch_bounds__(256) void rbf_kernel(
    const unsigned short* __restrict__ Dw, const float* __restrict__ gsum,
    const float* __restrict__ mult, float* __restrict__ out) {
  const float bw = *gsum * (1.0f / ((float)N_PTS * (float)(N_PTS - 1)));
  float c[NFEAT];
#pragma unroll
  for (int f = 0; f < NFEAT; ++f) c[f] = -1.0f / (bw * mult[f]);

  const int b = blockIdx.x;       // 0..1023 tile id
  const int bm = b >> 5, bn = b & 31;
  const int tid = threadIdx.x;
  const int lane = tid & 63;
  const int wid = tid >> 6;
  const int wave_m = wid >> 1, wave_n = wid & 1;
  const int lhi = lane >> 4, llo = lane & 15;

  const size_t tile_base = (size_t)b * 16384 + (size_t)wid * 4096;
  const int gi0 = bm * 128 + wave_m * 64 + lhi * 4;
  const int gj0 = bn * 128 + wave_n * 64 + llo;

#pragma unroll
  for (int i = 0; i < 4; ++i) {
    const unsigned short* src = Dw + tile_base + (size_t)i * 1024;
    const uint4 q0 = *(const uint4*)(src + lane * 8);
    const uint4 q1 = *(const uint4*)(src + 512 + lane * 8);
    float v[16];
    bf2f2(q0.x, v[0], v[1]);   bf2f2(q0.y, v[2], v[3]);
    bf2f2(q0.z, v[4], v[5]);   bf2f2(q0.w, v[6], v[7]);
    bf2f2(q1.x, v[8], v[9]);   bf2f2(q1.y, v[10], v[11]);
    bf2f2(q1.z, v[12], v[13]); bf2f2(q1.w, v[14], v[15]);

    float o[16];
#pragma unroll
    for (int e = 0; e < 16; ++e) {
      float a = 0.f;
#pragma unroll
      for (int f = 0; f < NFEAT; ++f) a += __expf(v[e] * c[f]);
      o[e] = a;
    }

#pragma unroll
    for (int rr = 0; rr < 4; ++rr) {
      float* orow = out + (size_t)(gi0 + i * 16 + rr) * N_PTS + gj0;
#pragma unroll
      for (int j = 0; j < 4; ++j) orow[j * 16] = o[rr * 4 + j];
    }
  }
}

extern "C" void kernel_launch(void* const* d_in, const int* in_sizes, int n_in,
                              void* d_out, int out_size, void* d_ws, size_t ws_size,
                              hipStream_t stream) {
  const float* X = (const float*)d_in[0];
  const float* mult = (const float*)d_in[1];
  float* out = (float*)d_out;

  // ws: gsum@0 | sq@1024 (16KB) | Xb@17408 (4MB) | Dw bf16 @4211712 (32MB)
  char* ws = (char*)d_ws;
  float* gsum = (float*)ws;
  float* sq = (float*)(ws + 1024);
  short* Xb = (short*)(ws + 1024 + N_PTS * sizeof(float));
  unsigned short* Dw = (unsigned short*)(ws + 1024 + N_PTS * sizeof(float) +
                                         (size_t)N_PTS * KDIM * sizeof(short));

  prep_kernel<<<N_PTS, 256, 0, stream>>>(X, Xb, sq, gsum);
  dist_kernel<<<dim3(32, 32), 256, 0, stream>>>(Xb, sq, Dw, gsum);
  rbf_kernel<<<1024, 256, 0, stream>>>(Dw, gsum, mult, out);
}